// Round 4
// baseline (360.816 us; speedup 1.0000x reference)
//
#include <hip/hip_runtime.h>

#define BB 8
#define NN 2048
#define FIN 256
#define FO 64

typedef short short8_t __attribute__((ext_vector_type(8)));
typedef float float4_t __attribute__((ext_vector_type(4)));
typedef int int4_v __attribute__((ext_vector_type(4)));

__device__ __forceinline__ unsigned short f2bf(float x) {
  unsigned int u = __float_as_uint(x);
  unsigned int r = (u + 0x7fffu + ((u >> 16) & 1u)) >> 16;
  return (unsigned short)r;
}

#define GLD16(gp, lp)                                                          \
  __builtin_amdgcn_global_load_lds(                                            \
      (const __attribute__((address_space(1))) void*)(gp),                     \
      (__attribute__((address_space(3))) void*)(lp), 16, 0, 0)

// ---------------- K0: compress adj (int32 0/1, 128 MiB) -> bitmask (4 MiB) --
// Pure stream: nt loads (don't evict ntp/u from L3), thread g owns elems
// 32g..32g+31 (8 int4 loads covering 2 full lines/lane), one uint store.
// Its measured BW calibrates the adj-stream ceiling.
__global__ __launch_bounds__(512) void k0_bits(
    const int* __restrict__ adj, unsigned int* __restrict__ abits)
{
  size_t g = (size_t)blockIdx.x * 512 + threadIdx.x;
  const int4_v* ap = (const int4_v*)adj + g * 8;
  int4_v a[8];
  #pragma unroll
  for (int e = 0; e < 8; ++e) a[e] = __builtin_nontemporal_load(ap + e);
  unsigned int m = 0;
  #pragma unroll
  for (int e = 0; e < 8; ++e) {
    m |= (a[e].x > 0 ? 1u : 0u) << (4 * e);
    m |= (a[e].y > 0 ? 1u : 0u) << (4 * e + 1);
    m |= (a[e].z > 0 ? 1u : 0u) << (4 * e + 2);
    m |= (a[e].w > 0 ? 1u : 0u) << (4 * e + 3);
  }
  abits[g] = m;
}

// ---------------- K1: Wh = h@W ; f1 ; f2 ; V = Wh*level ; zero scol ---------
__global__ __launch_bounds__(256) void k1_gemm(
    const float* __restrict__ h,
    const float* __restrict__ level,
    const float* __restrict__ W,
    const float* __restrict__ a,
    float* __restrict__ V, float* __restrict__ f1, float* __restrict__ f2,
    float* __restrict__ scol)
{
  __shared__ float wlds[128 * 64];
  __shared__ float hs[16 * 260];
  __shared__ float parts1[16 * 17];
  __shared__ float parts2[16 * 17];
  int t = threadIdx.x;
  int b = blockIdx.x >> 7;
  int i0 = (blockIdx.x & 127) * 16;

  if (blockIdx.x < 64) scol[blockIdx.x * 256 + t] = 0.0f;  // fallback path only

  {
    int r_ld = t >> 4, f0 = (t & 15) * 16;
    const float* hp = h + (size_t)(b * NN + i0 + r_ld) * FIN + f0;
    float4 x0 = *(const float4*)(hp);
    float4 x1 = *(const float4*)(hp + 4);
    float4 x2 = *(const float4*)(hp + 8);
    float4 x3 = *(const float4*)(hp + 12);
    float* hd = &hs[r_ld * 260 + f0];
    *(float4*)(hd + 0) = x0; *(float4*)(hd + 4) = x1;
    *(float4*)(hd + 8) = x2; *(float4*)(hd + 12) = x3;
  }

  int r = t >> 4;
  int c4 = (t & 15) * 4;
  float4 acc = {0, 0, 0, 0};

  #pragma unroll
  for (int half = 0; half < 2; ++half) {
    __syncthreads();
    #pragma unroll
    for (int q = 0; q < 8; ++q) {
      int idx = q * 1024 + t * 4;
      *(float4*)&wlds[idx] = *(const float4*)&W[half * 8192 + idx];
    }
    __syncthreads();
    for (int f = 0; f < 128; f += 8) {
      float4 hv0 = *(const float4*)&hs[r * 260 + half * 128 + f];
      float4 hv1 = *(const float4*)&hs[r * 260 + half * 128 + f + 4];
      float hvv[8] = {hv0.x, hv0.y, hv0.z, hv0.w, hv1.x, hv1.y, hv1.z, hv1.w};
      #pragma unroll
      for (int k = 0; k < 8; ++k) {
        float4 wv = *(const float4*)&wlds[(f + k) * 64 + c4];
        acc.x += hvv[k] * wv.x; acc.y += hvv[k] * wv.y;
        acc.z += hvv[k] * wv.z; acc.w += hvv[k] * wv.w;
      }
    }
  }

  float p1 = acc.x * a[c4] + acc.y * a[c4 + 1] + acc.z * a[c4 + 2] + acc.w * a[c4 + 3];
  float p2 = acc.x * a[64 + c4] + acc.y * a[64 + c4 + 1] +
             acc.z * a[64 + c4 + 2] + acc.w * a[64 + c4 + 3];
  parts1[r * 17 + (t & 15)] = p1;
  parts2[r * 17 + (t & 15)] = p2;
  __syncthreads();
  if (t < 16) {
    float s1 = 0.f, s2 = 0.f;
    #pragma unroll
    for (int g = 0; g < 16; ++g) { s1 += parts1[t * 17 + g]; s2 += parts2[t * 17 + g]; }
    f1[b * NN + i0 + t] = s1;
    f2[b * NN + i0 + t] = s2;
  }

  float lv = level[b * NN + i0 + r];
  float4 vv = {acc.x * lv, acc.y * lv, acc.z * lv, acc.w * lv};
  *(float4*)&V[(size_t)(b * NN + i0 + r) * FO + c4] = vv;
}

// ---------------- K2a (big2): ntp stream + LDS bit tile, NO adj read -------
// grid 512 (8 b x 64 32-row blocks), 512 threads. Thread t owns columns
// 4t..4t+3. adj replaced by an 8 KB bit tile staged once per block.
// Traffic: ntp 128 MiB (L3-warm) + bits 8 KB/blk + u 64 MiB + partials 4.
__global__ __launch_bounds__(512) void k2a_stream(
    const unsigned int* __restrict__ abits,
    const float* __restrict__ ntp,
    const float* __restrict__ f1,
    const float* __restrict__ f2,
    unsigned short* __restrict__ u_bf,
    float* __restrict__ partials)
{
  __shared__ unsigned int lbits[32 * 64];  // 32 rows x 2048 bits = 8 KB
  __shared__ float sf1[32];
  int t = threadIdx.x;
  int b = blockIdx.x >> 6;
  int rowblk = blockIdx.x & 63;
  int row0 = rowblk * 32;
  size_t base = (size_t)b * NN;
  int j0 = t * 4;

  {  // stage bit tile (one coalesced uint4/thread) + f1 slice
    const uint4* src = (const uint4*)(abits + (base + row0) * 64);
    ((uint4*)lbits)[t] = src[t];
    if (t < 32) sf1[t] = f1[base + row0 + t];
  }

  float4 f2v = *(const float4*)(f2 + base + j0);
  float acc0 = 0.f, acc1 = 0.f, acc2 = 0.f, acc3 = 0.f;

  size_t rb = (base + row0) * (size_t)NN + j0;
  const float* np = ntp + rb;
  unsigned short* up = u_bf + rb;
  int wrd = t >> 3;            // word index within a row's 64 bit-words
  int sh = (t & 7) * 4;        // nibble for columns j0..j0+3

  __syncthreads();

  #pragma unroll
  for (int g = 0; g < 4; ++g) {
    float4 nv[8];
    #pragma unroll
    for (int rr = 0; rr < 8; ++rr)
      nv[rr] = *(const float4*)(np + (size_t)(g * 8 + rr) * NN);
    #pragma unroll
    for (int rr = 0; rr < 8; ++rr) {
      int r = g * 8 + rr;
      unsigned int nib = lbits[r * 64 + wrd] >> sh;
      float f1v = sf1[r];
      float x0 = f1v + f2v.x; x0 = fmaxf(x0, 0.2f * x0);
      float x1 = f1v + f2v.y; x1 = fmaxf(x1, 0.2f * x1);
      float x2 = f1v + f2v.z; x2 = fmaxf(x2, 0.2f * x2);
      float x3 = f1v + f2v.w; x3 = fmaxf(x3, 0.2f * x3);
      float u0 = (nib & 1u) ? __expf(x0 * nv[rr].x) : 0.0f;
      float u1 = (nib & 2u) ? __expf(x1 * nv[rr].y) : 0.0f;
      float u2 = (nib & 4u) ? __expf(x2 * nv[rr].z) : 0.0f;
      float u3 = (nib & 8u) ? __expf(x3 * nv[rr].w) : 0.0f;
      acc0 += u0; acc1 += u1; acc2 += u2; acc3 += u3;
      unsigned int p0 = (unsigned int)f2bf(u0) | ((unsigned int)f2bf(u1) << 16);
      unsigned int p1 = (unsigned int)f2bf(u2) | ((unsigned int)f2bf(u3) << 16);
      *(uint2*)(up + (size_t)r * NN) = make_uint2(p0, p1);
    }
  }

  *(float4*)(partials + (size_t)(b * 64 + rowblk) * NN + j0) =
      make_float4(acc0, acc1, acc2, acc3);
}

// ---------------- K2a (mid): round-2 adj-direct stream ----------------------
__global__ __launch_bounds__(512) void k2a_stream_adj(
    const int* __restrict__ adj,
    const float* __restrict__ ntp,
    const float* __restrict__ f1,
    const float* __restrict__ f2,
    unsigned short* __restrict__ u_bf,
    float* __restrict__ partials)
{
  int t = threadIdx.x;
  int b = blockIdx.x >> 6;
  int rowblk = blockIdx.x & 63;
  int row0 = rowblk * 32;
  size_t base = (size_t)b * NN;
  int j0 = t * 4;

  float4 f2v = *(const float4*)(f2 + base + j0);
  float acc0 = 0.f, acc1 = 0.f, acc2 = 0.f, acc3 = 0.f;

  size_t rb = (base + row0) * (size_t)NN + j0;
  const int* ap = adj + rb;
  const float* np = ntp + rb;
  unsigned short* up = u_bf + rb;
  const float* f1p = f1 + base + row0;

  #pragma unroll
  for (int g = 0; g < 4; ++g) {
    int4 av[8];
    float4 nv[8];
    #pragma unroll
    for (int rr = 0; rr < 8; ++rr) {
      av[rr] = *(const int4*)(ap + (size_t)(g * 8 + rr) * NN);
      nv[rr] = *(const float4*)(np + (size_t)(g * 8 + rr) * NN);
    }
    #pragma unroll
    for (int rr = 0; rr < 8; ++rr) {
      float f1v = f1p[g * 8 + rr];
      float x0 = f1v + f2v.x; x0 = fmaxf(x0, 0.2f * x0);
      float x1 = f1v + f2v.y; x1 = fmaxf(x1, 0.2f * x1);
      float x2 = f1v + f2v.z; x2 = fmaxf(x2, 0.2f * x2);
      float x3 = f1v + f2v.w; x3 = fmaxf(x3, 0.2f * x3);
      float u0 = (av[rr].x > 0) ? __expf(x0 * nv[rr].x) : 0.0f;
      float u1 = (av[rr].y > 0) ? __expf(x1 * nv[rr].y) : 0.0f;
      float u2 = (av[rr].z > 0) ? __expf(x2 * nv[rr].z) : 0.0f;
      float u3 = (av[rr].w > 0) ? __expf(x3 * nv[rr].w) : 0.0f;
      acc0 += u0; acc1 += u1; acc2 += u2; acc3 += u3;
      unsigned int p0 = (unsigned int)f2bf(u0) | ((unsigned int)f2bf(u1) << 16);
      unsigned int p1 = (unsigned int)f2bf(u2) | ((unsigned int)f2bf(u3) << 16);
      *(uint2*)(up + (size_t)(g * 8 + rr) * NN) = make_uint2(p0, p1);
    }
  }

  *(float4*)(partials + (size_t)(b * 64 + rowblk) * NN + j0) =
      make_float4(acc0, acc1, acc2, acc3);
}

// ---------------- K2a (fallback): column sums + bits (unchanged) ------------
template <int STORE_U>
__global__ __launch_bounds__(512) void k2a_stats(
    const int* __restrict__ adj,
    const float* __restrict__ ntp,
    const float* __restrict__ f1,
    const float* __restrict__ f2,
    unsigned short* __restrict__ u_bf,
    unsigned char* __restrict__ bits,
    float* __restrict__ scol)
{
  __shared__ int ladj[2][16 * 256];   // 32 KB
  __shared__ float lnt[2][16 * 256];  // 32 KB
  __shared__ float red[2048];         // 8 KB
  int t = threadIdx.x;
  int b = blockIdx.x >> 6;
  int row0 = (blockIdx.x & 63) * 32;
  int w = t >> 6, l = t & 63;
  size_t base = (size_t)b * NN;

  auto stage = [&](int buf, int s) {
    int tile = s >> 3, c = s & 7;
    int r0 = row0 + tile * 16 + 2 * w;
    const int* ga = adj + (base + r0) * NN + c * 256 + l * 4;
    const float* gn = ntp + (base + r0) * NN + c * 256 + l * 4;
    GLD16(ga, &ladj[buf][(2 * w) * 256]);
    GLD16(ga + NN, &ladj[buf][(2 * w + 1) * 256]);
    GLD16(gn, &lnt[buf][(2 * w) * 256]);
    GLD16(gn + NN, &lnt[buf][(2 * w + 1) * 256]);
  };

  int jj = t & 255;
  int rh = t >> 8;

  float accJ[8];
  #pragma unroll
  for (int c = 0; c < 8; ++c) accJ[c] = 0.f;
  float f2v[8];
  #pragma unroll
  for (int c = 0; c < 8; ++c) f2v[c] = f2[base + c * 256 + jj];

  stage(0, 0);
  for (int s = 0; s < 16; ++s) {
    int buf = s & 1;
    __syncthreads();
    if (s < 15) stage(buf ^ 1, s + 1);
    int tile = s >> 3, c = s & 7;
    #pragma unroll
    for (int q = 0; q < 8; ++q) {
      int r = rh * 8 + q;
      int av = ladj[buf][r * 256 + jj];
      float nv = lnt[buf][r * 256 + jj];
      float f1v = f1[base + row0 + tile * 16 + r];
      float x = f1v + f2v[c];
      x = fmaxf(x, 0.2f * x);            // leaky_relu slope 0.2
      bool m = av > 0;
      float u = m ? __expf(x * nv) : 0.0f;
      accJ[c] += u;
      if (STORE_U) {
        u_bf[(base + row0 + tile * 16 + r) * NN + c * 256 + jj] = f2bf(u);
      } else {
        unsigned long long bal = __ballot(m);
        if (l == 0)
          *(unsigned long long*)&bits[(base + row0 + tile * 16 + r) * (NN / 8)
                                      + c * 32 + (w & 3) * 8] = bal;
      }
    }
  }

  if (rh == 0) {
    #pragma unroll
    for (int c = 0; c < 8; ++c) red[c * 256 + jj] = accJ[c];
  }
  __syncthreads();
  if (rh == 1) {
    #pragma unroll
    for (int c = 0; c < 8; ++c) red[c * 256 + jj] += accJ[c];
  }
  __syncthreads();
  #pragma unroll
  for (int q = 0; q < 4; ++q)
    atomicAdd(&scol[base + q * 512 + t], red[q * 512 + t]);
}

// ---------------- K2b (big): reduce partials -> 1/s ; pack V' ---------------
__global__ __launch_bounds__(256) void k2b_pack_p(
    const float* __restrict__ V,
    const float* __restrict__ partials,
    unsigned short* __restrict__ vf)
{
  __shared__ float sred[8 * 32];
  __shared__ float sinv[32];
  int t = threadIdx.x;
  int b = blockIdx.x >> 6;
  int kk = blockIdx.x & 63;

  {
    int tj = t & 31, tr = t >> 5;     // 8 rowblk-groups of 8
    float s = 0.f;
    #pragma unroll
    for (int q = 0; q < 8; ++q)
      s += partials[(size_t)(b * 64 + tr * 8 + q) * NN + kk * 32 + tj];
    sred[tr * 32 + tj] = s;
  }
  __syncthreads();
  if (t < 32) {
    float tot = 0.f;
    #pragma unroll
    for (int g = 0; g < 8; ++g) tot += sred[g * 32 + t];
    sinv[t] = (tot > 0.f) ? (1.0f / tot) : 0.0f;
  }
  __syncthreads();

  int ng = t >> 6;
  int l = t & 63;
  int jb0 = (l >> 4) * 8;             // 0,8,16,24 within the 32-col group
  int jb = kk * 32 + jb0;
  int o = ng * 16 + (l & 15);
  unsigned int pk[4];
  #pragma unroll
  for (int p = 0; p < 4; ++p) {
    int jr0 = jb + 2 * p, jr1 = jb + 2 * p + 1;
    float i0 = sinv[jb0 + 2 * p];
    float i1 = sinv[jb0 + 2 * p + 1];
    float v0 = V[(size_t)(b * NN + jr0) * FO + o] * i0;
    float v1 = V[(size_t)(b * NN + jr1) * FO + o] * i1;
    pk[p] = (unsigned int)f2bf(v0) | ((unsigned int)f2bf(v1) << 16);
  }
  *(uint4*)(vf + (size_t)(((b * 64 + kk) * 4 + ng) * 64 + l) * 8) =
      make_uint4(pk[0], pk[1], pk[2], pk[3]);
}

// ---------------- K2b (fallback): pack from scol (unchanged) ----------------
__global__ __launch_bounds__(256) void k2b_pack(
    const float* __restrict__ V,
    const float* __restrict__ scol,
    unsigned short* __restrict__ vf)
{
  int t = threadIdx.x;
  int b = blockIdx.x >> 6;
  int kk = blockIdx.x & 63;
  int ng = t >> 6;
  int l = t & 63;
  int jb = kk * 32 + ((l >> 4) * 8);
  int o = ng * 16 + (l & 15);
  unsigned int pk[4];
  #pragma unroll
  for (int p = 0; p < 4; ++p) {
    int jr0 = jb + 2 * p, jr1 = jb + 2 * p + 1;
    float s0 = scol[b * NN + jr0];
    float s1 = scol[b * NN + jr1];
    float i0 = (s0 > 0.f) ? (1.0f / s0) : 0.0f;
    float i1 = (s1 > 0.f) ? (1.0f / s1) : 0.0f;
    float v0 = V[(size_t)(b * NN + jr0) * FO + o] * i0;
    float v1 = V[(size_t)(b * NN + jr1) * FO + o] * i1;
    pk[p] = (unsigned int)f2bf(v0) | ((unsigned int)f2bf(v1) << 16);
  }
  *(uint4*)(vf + (size_t)(((b * 64 + kk) * 4 + ng) * 64 + l) * 8) =
      make_uint4(pk[0], pk[1], pk[2], pk[3]);
}

// ---------------- K3: out = relu(U @ V'), 32-row tiles ----------------------
__global__ __launch_bounds__(512, 4) void k3_agg_u3(
    const unsigned short* __restrict__ u_bf,
    const unsigned short* __restrict__ vf,
    float* __restrict__ outp)
{
  __shared__ float red[8 * 16 * 68];   // 34.8 KB
  int t = threadIdx.x;
  int b = blockIdx.x >> 6;
  int tt = blockIdx.x & 63;
  int i0 = tt * 32;
  int w = t >> 6, l = t & 63;
  int col = l & 15, quad = l >> 4;
  const unsigned short* urow0 = u_bf + (size_t)(b * NN + i0 + col) * NN + quad * 8;
  const unsigned short* urow1 = urow0 + (size_t)16 * NN;
  const unsigned short* vbase = vf + (size_t)(b * 64) * 2048 + l * 8;

  float4_t acc[2][4];
  #pragma unroll
  for (int sgi = 0; sgi < 2; ++sgi)
    #pragma unroll
    for (int g = 0; g < 4; ++g) acc[sgi][g] = (float4_t){0, 0, 0, 0};

  int kk0 = w * 8;
  short8_t A0 = *(const short8_t*)(urow0 + kk0 * 32);
  short8_t A1 = *(const short8_t*)(urow1 + kk0 * 32);
  const unsigned short* vb0 = vbase + (size_t)kk0 * 2048;
  short8_t c0 = *(const short8_t*)(vb0);
  short8_t c1 = *(const short8_t*)(vb0 + 512);
  short8_t c2 = *(const short8_t*)(vb0 + 1024);
  short8_t c3 = *(const short8_t*)(vb0 + 1536);

  #pragma unroll
  for (int s = 0; s < 8; ++s) {
    short8_t nA0, nA1, n0, n1, n2, n3;
    if (s < 7) {
      int kk = w * 8 + s + 1;
      nA0 = *(const short8_t*)(urow0 + kk * 32);
      nA1 = *(const short8_t*)(urow1 + kk * 32);
      const unsigned short* vn = vbase + (size_t)kk * 2048;
      n0 = *(const short8_t*)(vn);
      n1 = *(const short8_t*)(vn + 512);
      n2 = *(const short8_t*)(vn + 1024);
      n3 = *(const short8_t*)(vn + 1536);
    }
    acc[0][0] = __builtin_amdgcn_mfma_f32_16x16x32_bf16(A0, c0, acc[0][0], 0, 0, 0);
    acc[0][1] = __builtin_amdgcn_mfma_f32_16x16x32_bf16(A0, c1, acc[0][1], 0, 0, 0);
    acc[0][2] = __builtin_amdgcn_mfma_f32_16x16x32_bf16(A0, c2, acc[0][2], 0, 0, 0);
    acc[0][3] = __builtin_amdgcn_mfma_f32_16x16x32_bf16(A0, c3, acc[0][3], 0, 0, 0);
    acc[1][0] = __builtin_amdgcn_mfma_f32_16x16x32_bf16(A1, c0, acc[1][0], 0, 0, 0);
    acc[1][1] = __builtin_amdgcn_mfma_f32_16x16x32_bf16(A1, c1, acc[1][1], 0, 0, 0);
    acc[1][2] = __builtin_amdgcn_mfma_f32_16x16x32_bf16(A1, c2, acc[1][2], 0, 0, 0);
    acc[1][3] = __builtin_amdgcn_mfma_f32_16x16x32_bf16(A1, c3, acc[1][3], 0, 0, 0);
    if (s < 7) { A0 = nA0; A1 = nA1; c0 = n0; c1 = n1; c2 = n2; c3 = n3; }
  }

  #pragma unroll
  for (int sub = 0; sub < 2; ++sub) {
    __syncthreads();
    #pragma unroll
    for (int r = 0; r < 4; ++r) {
      int rowi = quad * 4 + r;
      float* rp = &red[w * 1088 + rowi * 68 + col];
      rp[0] = acc[sub][0][r];
      rp[16] = acc[sub][1][r];
      rp[32] = acc[sub][2][r];
      rp[48] = acc[sub][3][r];
    }
    __syncthreads();
    if (t < 256) {
      int row = t >> 4, o4 = (t & 15) * 4;
      const float* rp = &red[row * 68 + o4];
      float4 s0 = *(const float4*)(rp);
      float4 s1 = *(const float4*)(rp + 1088);
      float4 s2 = *(const float4*)(rp + 2176);
      float4 s3 = *(const float4*)(rp + 3264);
      float4 s4 = *(const float4*)(rp + 4352);
      float4 s5 = *(const float4*)(rp + 5440);
      float4 s6 = *(const float4*)(rp + 6528);
      float4 s7 = *(const float4*)(rp + 7616);
      float4 o;
      o.x = fmaxf(s0.x + s1.x + s2.x + s3.x + s4.x + s5.x + s6.x + s7.x, 0.0f);
      o.y = fmaxf(s0.y + s1.y + s2.y + s3.y + s4.y + s5.y + s6.y + s7.y, 0.0f);
      o.z = fmaxf(s0.z + s1.z + s2.z + s3.z + s4.z + s5.z + s6.z + s7.z, 0.0f);
      o.w = fmaxf(s0.w + s1.w + s2.w + s3.w + s4.w + s5.w + s6.w + s7.w, 0.0f);
      *(float4*)&outp[(size_t)(b * NN + i0 + sub * 16 + row) * FO + o4] = o;
    }
  }
}

// ---------------- K3b: fallback — recompute u from nt/f1/f2/bits -----------
__global__ __launch_bounds__(256) void k3_agg_b(
    const float* __restrict__ ntp,
    const unsigned char* __restrict__ bits,
    const float* __restrict__ f1,
    const float* __restrict__ f2,
    const unsigned short* __restrict__ vf,
    float* __restrict__ outp)
{
  __shared__ float red[4 * 16 * 68];
  int t = threadIdx.x;
  int b = blockIdx.x >> 7;
  int i0 = (blockIdx.x & 127) * 16;
  int w = t >> 6, l = t & 63;
  int col = l & 15, quad = l >> 4;
  int gi = b * NN + i0 + col;
  float f1v = f1[gi];
  const float* ntrow = ntp + (size_t)gi * NN;
  const unsigned char* brow = bits + (size_t)gi * (NN / 8);
  float4_t acc0 = {0, 0, 0, 0}, acc1 = {0, 0, 0, 0}, acc2 = {0, 0, 0, 0}, acc3 = {0, 0, 0, 0};

  for (int s = 0; s < 16; ++s) {
    int kk = w * 16 + s;
    int jq = kk * 32 + quad * 8;
    unsigned int m8 = brow[jq >> 3];
    float4 n0 = *(const float4*)(ntrow + jq);
    float4 n1 = *(const float4*)(ntrow + jq + 4);
    float4 g0 = *(const float4*)(f2 + b * NN + jq);
    float4 g1 = *(const float4*)(f2 + b * NN + jq + 4);
    float f2v[8] = {g0.x, g0.y, g0.z, g0.w, g1.x, g1.y, g1.z, g1.w};
    float ntf[8] = {n0.x, n0.y, n0.z, n0.w, n1.x, n1.y, n1.z, n1.w};
    union { unsigned int u[4]; short8_t v; } A;
    #pragma unroll
    for (int p = 0; p < 4; ++p) {
      int e0 = 2 * p, e1 = 2 * p + 1;
      float x0 = f1v + f2v[e0]; x0 = fmaxf(x0, 0.2f * x0);
      float u0 = ((m8 >> e0) & 1u) ? __expf(x0 * ntf[e0]) : 0.0f;
      float x1 = f1v + f2v[e1]; x1 = fmaxf(x1, 0.2f * x1);
      float u1 = ((m8 >> e1) & 1u) ? __expf(x1 * ntf[e1]) : 0.0f;
      A.u[p] = (unsigned int)f2bf(u0) | ((unsigned int)f2bf(u1) << 16);
    }
    const unsigned short* vb = vf + (size_t)(b * 64 + kk) * 2048 + l * 8;
    short8_t bf0 = *(const short8_t*)(vb);
    short8_t bf1 = *(const short8_t*)(vb + 512);
    short8_t bf2 = *(const short8_t*)(vb + 1024);
    short8_t bf3 = *(const short8_t*)(vb + 1536);
    acc0 = __builtin_amdgcn_mfma_f32_16x16x32_bf16(A.v, bf0, acc0, 0, 0, 0);
    acc1 = __builtin_amdgcn_mfma_f32_16x16x32_bf16(A.v, bf1, acc1, 0, 0, 0);
    acc2 = __builtin_amdgcn_mfma_f32_16x16x32_bf16(A.v, bf2, acc2, 0, 0, 0);
    acc3 = __builtin_amdgcn_mfma_f32_16x16x32_bf16(A.v, bf3, acc3, 0, 0, 0);
  }

  #pragma unroll
  for (int r = 0; r < 4; ++r) {
    int rowi = quad * 4 + r;
    red[w * 1088 + rowi * 68 + 0 + col] = acc0[r];
    red[w * 1088 + rowi * 68 + 16 + col] = acc1[r];
    red[w * 1088 + rowi * 68 + 32 + col] = acc2[r];
    red[w * 1088 + rowi * 68 + 48 + col] = acc3[r];
  }
  __syncthreads();

  int row = t >> 4, o4 = (t & 15) * 4;
  const float* rp = &red[row * 68 + o4];
  float4 s0 = *(const float4*)(rp);
  float4 s1 = *(const float4*)(rp + 1088);
  float4 s2 = *(const float4*)(rp + 2176);
  float4 s3 = *(const float4*)(rp + 3264);
  float4 o;
  o.x = fmaxf(s0.x + s1.x + s2.x + s3.x, 0.0f);
  o.y = fmaxf(s0.y + s1.y + s2.y + s3.y, 0.0f);
  o.z = fmaxf(s0.z + s1.z + s2.z + s3.z, 0.0f);
  o.w = fmaxf(s0.w + s1.w + s2.w + s3.w, 0.0f);
  *(float4*)&outp[(size_t)(b * NN + i0 + row) * FO + o4] = o;
}

extern "C" void kernel_launch(void* const* d_in, const int* in_sizes, int n_in,
                              void* d_out, int out_size, void* d_ws, size_t ws_size,
                              hipStream_t stream) {
  const float* h = (const float*)d_in[0];       // fp32 [B,N,FIN]
  const int* adj = (const int*)d_in[1];         // int32 [B,N,N]
  const float* level = (const float*)d_in[2];   // fp32 [B,N]
  const float* ntm = (const float*)d_in[3];     // fp32 [B,N,N]
  const float* W = (const float*)d_in[4];       // fp32 [FIN,FO]
  const float* a = (const float*)d_in[5];       // fp32 [2*FO,1]
  float* outp = (float*)d_out;

  float* V = (float*)d_ws;                              // 4 MB
  float* f1 = V + (size_t)BB * NN * FO;                 // 64 KB
  float* f2 = f1 + BB * NN;                             // 64 KB
  float* scol = f2 + BB * NN;                           // 64 KB (fallback)
  unsigned short* vf = (unsigned short*)(scol + BB * NN); // 2 MB
  float* partials = (float*)(vf + (size_t)BB * NN * FO);  // 4 MB
  unsigned int* abits = (unsigned int*)(partials + (size_t)BB * 64 * NN); // 4 MB
  char* tail = (char*)(abits + (size_t)BB * NN * (NN / 32));
  size_t fixed2 = (size_t)(tail - (char*)d_ws);
  size_t fixed1 = (size_t)((char*)abits - (char*)d_ws);
  size_t ubytes = (size_t)BB * NN * NN * 2;             // 67 MB
  bool big2 = (ws_size >= fixed2 + ubytes);
  bool big1 = (ws_size >= fixed1 + ubytes);

  k1_gemm<<<1024, 256, 0, stream>>>(h, level, W, a, V, f1, f2, scol);
  if (big2) {
    unsigned short* u_bf = (unsigned short*)tail;
    k0_bits<<<2048, 512, 0, stream>>>(adj, abits);
    k2a_stream<<<512, 512, 0, stream>>>(abits, ntm, f1, f2, u_bf, partials);
    k2b_pack_p<<<512, 256, 0, stream>>>(V, partials, vf);
    k3_agg_u3<<<512, 512, 0, stream>>>(u_bf, vf, outp);
  } else if (big1) {
    unsigned short* u_bf = (unsigned short*)abits;
    k2a_stream_adj<<<512, 512, 0, stream>>>(adj, ntm, f1, f2, u_bf, partials);
    k2b_pack_p<<<512, 256, 0, stream>>>(V, partials, vf);
    k3_agg_u3<<<512, 512, 0, stream>>>(u_bf, vf, outp);
  } else {
    unsigned char* bits = (unsigned char*)abits;        // 4 MB
    k2a_stats<0><<<512, 512, 0, stream>>>(adj, ntm, f1, f2, nullptr, bits, scol);
    k2b_pack<<<512, 256, 0, stream>>>(V, scol, vf);
    k3_agg_b<<<1024, 256, 0, stream>>>(ntm, bits, f1, f2, vf, outp);
  }
}

// Round 5
// 326.869 us; speedup vs baseline: 1.1039x; 1.1039x over previous
//
#include <hip/hip_runtime.h>

#define BB 8
#define NN 2048
#define FIN 256
#define FO 64

typedef short short8_t __attribute__((ext_vector_type(8)));
typedef float float4_t __attribute__((ext_vector_type(4)));
typedef int int4_v __attribute__((ext_vector_type(4)));

__device__ __forceinline__ unsigned short f2bf(float x) {
  unsigned int u = __float_as_uint(x);
  unsigned int r = (u + 0x7fffu + ((u >> 16) & 1u)) >> 16;
  return (unsigned short)r;
}

#define GLD16(gp, lp)                                                          \
  __builtin_amdgcn_global_load_lds(                                            \
      (const __attribute__((address_space(1))) void*)(gp),                     \
      (__attribute__((address_space(3))) void*)(lp), 16, 0, 0)

// ---------------- K1 fused: [blocks 0..1023] Wh=h@W; f1; f2; V=Wh*level -----
//                 [blocks 1024..5119] adj (128 MiB) -> abits (4 MiB) ---------
// The adj cold-stream (~60 us at the ~2.2 TB/s per-CU read-miss wall) and the
// GEMM (VALU/LDS-bound, ~20 us) have no data/dep overlap: co-scheduling them
// hides the GEMM inside the stream instead of paying them sequentially.
__global__ __launch_bounds__(256) void k1_fused(
    const float* __restrict__ h,
    const float* __restrict__ level,
    const float* __restrict__ W,
    const float* __restrict__ a,
    float* __restrict__ V, float* __restrict__ f1, float* __restrict__ f2,
    float* __restrict__ scol,
    const int* __restrict__ adj,
    unsigned int* __restrict__ abits)
{
  __shared__ float wlds[128 * 64];
  __shared__ float hs[16 * 260];
  __shared__ float parts1[16 * 17];
  __shared__ float parts2[16 * 17];
  int t = threadIdx.x;

  if (blockIdx.x >= 1024) {
    // -------- adj -> bits stream (4096 blocks x 256 threads, 32 elems/thr) --
    size_t g = (size_t)(blockIdx.x - 1024) * 256 + t;
    const int4_v* ap = (const int4_v*)adj + g * 8;
    int4_v av[8];
    #pragma unroll
    for (int e = 0; e < 8; ++e) av[e] = ap[e];
    unsigned int m = 0;
    #pragma unroll
    for (int e = 0; e < 8; ++e) {
      m |= (av[e].x > 0 ? 1u : 0u) << (4 * e);
      m |= (av[e].y > 0 ? 1u : 0u) << (4 * e + 1);
      m |= (av[e].z > 0 ? 1u : 0u) << (4 * e + 2);
      m |= (av[e].w > 0 ? 1u : 0u) << (4 * e + 3);
    }
    abits[g] = m;
    return;
  }

  int b = blockIdx.x >> 7;
  int i0 = (blockIdx.x & 127) * 16;

  if (blockIdx.x < 64) scol[blockIdx.x * 256 + t] = 0.0f;  // fallback path only

  {
    int r_ld = t >> 4, f0 = (t & 15) * 16;
    const float* hp = h + (size_t)(b * NN + i0 + r_ld) * FIN + f0;
    float4 x0 = *(const float4*)(hp);
    float4 x1 = *(const float4*)(hp + 4);
    float4 x2 = *(const float4*)(hp + 8);
    float4 x3 = *(const float4*)(hp + 12);
    float* hd = &hs[r_ld * 260 + f0];
    *(float4*)(hd + 0) = x0; *(float4*)(hd + 4) = x1;
    *(float4*)(hd + 8) = x2; *(float4*)(hd + 12) = x3;
  }

  int r = t >> 4;
  int c4 = (t & 15) * 4;
  float4 acc = {0, 0, 0, 0};

  #pragma unroll
  for (int half = 0; half < 2; ++half) {
    __syncthreads();
    #pragma unroll
    for (int q = 0; q < 8; ++q) {
      int idx = q * 1024 + t * 4;
      *(float4*)&wlds[idx] = *(const float4*)&W[half * 8192 + idx];
    }
    __syncthreads();
    for (int f = 0; f < 128; f += 8) {
      float4 hv0 = *(const float4*)&hs[r * 260 + half * 128 + f];
      float4 hv1 = *(const float4*)&hs[r * 260 + half * 128 + f + 4];
      float hvv[8] = {hv0.x, hv0.y, hv0.z, hv0.w, hv1.x, hv1.y, hv1.z, hv1.w};
      #pragma unroll
      for (int k = 0; k < 8; ++k) {
        float4 wv = *(const float4*)&wlds[(f + k) * 64 + c4];
        acc.x += hvv[k] * wv.x; acc.y += hvv[k] * wv.y;
        acc.z += hvv[k] * wv.z; acc.w += hvv[k] * wv.w;
      }
    }
  }

  float p1 = acc.x * a[c4] + acc.y * a[c4 + 1] + acc.z * a[c4 + 2] + acc.w * a[c4 + 3];
  float p2 = acc.x * a[64 + c4] + acc.y * a[64 + c4 + 1] +
             acc.z * a[64 + c4 + 2] + acc.w * a[64 + c4 + 3];
  parts1[r * 17 + (t & 15)] = p1;
  parts2[r * 17 + (t & 15)] = p2;
  __syncthreads();
  if (t < 16) {
    float s1 = 0.f, s2 = 0.f;
    #pragma unroll
    for (int g = 0; g < 16; ++g) { s1 += parts1[t * 17 + g]; s2 += parts2[t * 17 + g]; }
    f1[b * NN + i0 + t] = s1;
    f2[b * NN + i0 + t] = s2;
  }

  float lv = level[b * NN + i0 + r];
  float4 vv = {acc.x * lv, acc.y * lv, acc.z * lv, acc.w * lv};
  *(float4*)&V[(size_t)(b * NN + i0 + r) * FO + c4] = vv;
}

// ---------------- K2a (big2): ntp stream + LDS bit tile, NO adj read -------
__global__ __launch_bounds__(512) void k2a_stream(
    const unsigned int* __restrict__ abits,
    const float* __restrict__ ntp,
    const float* __restrict__ f1,
    const float* __restrict__ f2,
    unsigned short* __restrict__ u_bf,
    float* __restrict__ partials)
{
  __shared__ unsigned int lbits[32 * 64];  // 32 rows x 2048 bits = 8 KB
  __shared__ float sf1[32];
  int t = threadIdx.x;
  int b = blockIdx.x >> 6;
  int rowblk = blockIdx.x & 63;
  int row0 = rowblk * 32;
  size_t base = (size_t)b * NN;
  int j0 = t * 4;

  {  // stage bit tile (one coalesced uint4/thread) + f1 slice
    const uint4* src = (const uint4*)(abits + (base + row0) * 64);
    ((uint4*)lbits)[t] = src[t];
    if (t < 32) sf1[t] = f1[base + row0 + t];
  }

  float4 f2v = *(const float4*)(f2 + base + j0);
  float acc0 = 0.f, acc1 = 0.f, acc2 = 0.f, acc3 = 0.f;

  size_t rb = (base + row0) * (size_t)NN + j0;
  const float* np = ntp + rb;
  unsigned short* up = u_bf + rb;
  int wrd = t >> 3;            // word index within a row's 64 bit-words
  int sh = (t & 7) * 4;        // nibble for columns j0..j0+3

  __syncthreads();

  #pragma unroll
  for (int g = 0; g < 4; ++g) {
    float4 nv[8];
    #pragma unroll
    for (int rr = 0; rr < 8; ++rr)
      nv[rr] = *(const float4*)(np + (size_t)(g * 8 + rr) * NN);
    #pragma unroll
    for (int rr = 0; rr < 8; ++rr) {
      int r = g * 8 + rr;
      unsigned int nib = lbits[r * 64 + wrd] >> sh;
      float f1v = sf1[r];
      float x0 = f1v + f2v.x; x0 = fmaxf(x0, 0.2f * x0);
      float x1 = f1v + f2v.y; x1 = fmaxf(x1, 0.2f * x1);
      float x2 = f1v + f2v.z; x2 = fmaxf(x2, 0.2f * x2);
      float x3 = f1v + f2v.w; x3 = fmaxf(x3, 0.2f * x3);
      float u0 = (nib & 1u) ? __expf(x0 * nv[rr].x) : 0.0f;
      float u1 = (nib & 2u) ? __expf(x1 * nv[rr].y) : 0.0f;
      float u2 = (nib & 4u) ? __expf(x2 * nv[rr].z) : 0.0f;
      float u3 = (nib & 8u) ? __expf(x3 * nv[rr].w) : 0.0f;
      acc0 += u0; acc1 += u1; acc2 += u2; acc3 += u3;
      unsigned int p0 = (unsigned int)f2bf(u0) | ((unsigned int)f2bf(u1) << 16);
      unsigned int p1 = (unsigned int)f2bf(u2) | ((unsigned int)f2bf(u3) << 16);
      *(uint2*)(up + (size_t)r * NN) = make_uint2(p0, p1);
    }
  }

  *(float4*)(partials + (size_t)(b * 64 + rowblk) * NN + j0) =
      make_float4(acc0, acc1, acc2, acc3);
}

// ---------------- K2a (mid): adj-direct stream ------------------------------
__global__ __launch_bounds__(512) void k2a_stream_adj(
    const int* __restrict__ adj,
    const float* __restrict__ ntp,
    const float* __restrict__ f1,
    const float* __restrict__ f2,
    unsigned short* __restrict__ u_bf,
    float* __restrict__ partials)
{
  int t = threadIdx.x;
  int b = blockIdx.x >> 6;
  int rowblk = blockIdx.x & 63;
  int row0 = rowblk * 32;
  size_t base = (size_t)b * NN;
  int j0 = t * 4;

  float4 f2v = *(const float4*)(f2 + base + j0);
  float acc0 = 0.f, acc1 = 0.f, acc2 = 0.f, acc3 = 0.f;

  size_t rb = (base + row0) * (size_t)NN + j0;
  const int* ap = adj + rb;
  const float* np = ntp + rb;
  unsigned short* up = u_bf + rb;
  const float* f1p = f1 + base + row0;

  #pragma unroll
  for (int g = 0; g < 4; ++g) {
    int4 av[8];
    float4 nv[8];
    #pragma unroll
    for (int rr = 0; rr < 8; ++rr) {
      av[rr] = *(const int4*)(ap + (size_t)(g * 8 + rr) * NN);
      nv[rr] = *(const float4*)(np + (size_t)(g * 8 + rr) * NN);
    }
    #pragma unroll
    for (int rr = 0; rr < 8; ++rr) {
      float f1v = f1p[g * 8 + rr];
      float x0 = f1v + f2v.x; x0 = fmaxf(x0, 0.2f * x0);
      float x1 = f1v + f2v.y; x1 = fmaxf(x1, 0.2f * x1);
      float x2 = f1v + f2v.z; x2 = fmaxf(x2, 0.2f * x2);
      float x3 = f1v + f2v.w; x3 = fmaxf(x3, 0.2f * x3);
      float u0 = (av[rr].x > 0) ? __expf(x0 * nv[rr].x) : 0.0f;
      float u1 = (av[rr].y > 0) ? __expf(x1 * nv[rr].y) : 0.0f;
      float u2 = (av[rr].z > 0) ? __expf(x2 * nv[rr].z) : 0.0f;
      float u3 = (av[rr].w > 0) ? __expf(x3 * nv[rr].w) : 0.0f;
      acc0 += u0; acc1 += u1; acc2 += u2; acc3 += u3;
      unsigned int p0 = (unsigned int)f2bf(u0) | ((unsigned int)f2bf(u1) << 16);
      unsigned int p1 = (unsigned int)f2bf(u2) | ((unsigned int)f2bf(u3) << 16);
      *(uint2*)(up + (size_t)(g * 8 + rr) * NN) = make_uint2(p0, p1);
    }
  }

  *(float4*)(partials + (size_t)(b * 64 + rowblk) * NN + j0) =
      make_float4(acc0, acc1, acc2, acc3);
}

// ---------------- K2a (fallback): column sums + bits (unchanged) ------------
template <int STORE_U>
__global__ __launch_bounds__(512) void k2a_stats(
    const int* __restrict__ adj,
    const float* __restrict__ ntp,
    const float* __restrict__ f1,
    const float* __restrict__ f2,
    unsigned short* __restrict__ u_bf,
    unsigned char* __restrict__ bits,
    float* __restrict__ scol)
{
  __shared__ int ladj[2][16 * 256];   // 32 KB
  __shared__ float lnt[2][16 * 256];  // 32 KB
  __shared__ float red[2048];         // 8 KB
  int t = threadIdx.x;
  int b = blockIdx.x >> 6;
  int row0 = (blockIdx.x & 63) * 32;
  int w = t >> 6, l = t & 63;
  size_t base = (size_t)b * NN;

  auto stage = [&](int buf, int s) {
    int tile = s >> 3, c = s & 7;
    int r0 = row0 + tile * 16 + 2 * w;
    const int* ga = adj + (base + r0) * NN + c * 256 + l * 4;
    const float* gn = ntp + (base + r0) * NN + c * 256 + l * 4;
    GLD16(ga, &ladj[buf][(2 * w) * 256]);
    GLD16(ga + NN, &ladj[buf][(2 * w + 1) * 256]);
    GLD16(gn, &lnt[buf][(2 * w) * 256]);
    GLD16(gn + NN, &lnt[buf][(2 * w + 1) * 256]);
  };

  int jj = t & 255;
  int rh = t >> 8;

  float accJ[8];
  #pragma unroll
  for (int c = 0; c < 8; ++c) accJ[c] = 0.f;
  float f2v[8];
  #pragma unroll
  for (int c = 0; c < 8; ++c) f2v[c] = f2[base + c * 256 + jj];

  stage(0, 0);
  for (int s = 0; s < 16; ++s) {
    int buf = s & 1;
    __syncthreads();
    if (s < 15) stage(buf ^ 1, s + 1);
    int tile = s >> 3, c = s & 7;
    #pragma unroll
    for (int q = 0; q < 8; ++q) {
      int r = rh * 8 + q;
      int av = ladj[buf][r * 256 + jj];
      float nv = lnt[buf][r * 256 + jj];
      float f1v = f1[base + row0 + tile * 16 + r];
      float x = f1v + f2v[c];
      x = fmaxf(x, 0.2f * x);            // leaky_relu slope 0.2
      bool m = av > 0;
      float u = m ? __expf(x * nv) : 0.0f;
      accJ[c] += u;
      if (STORE_U) {
        u_bf[(base + row0 + tile * 16 + r) * NN + c * 256 + jj] = f2bf(u);
      } else {
        unsigned long long bal = __ballot(m);
        if (l == 0)
          *(unsigned long long*)&bits[(base + row0 + tile * 16 + r) * (NN / 8)
                                      + c * 32 + (w & 3) * 8] = bal;
      }
    }
  }

  if (rh == 0) {
    #pragma unroll
    for (int c = 0; c < 8; ++c) red[c * 256 + jj] = accJ[c];
  }
  __syncthreads();
  if (rh == 1) {
    #pragma unroll
    for (int c = 0; c < 8; ++c) red[c * 256 + jj] += accJ[c];
  }
  __syncthreads();
  #pragma unroll
  for (int q = 0; q < 4; ++q)
    atomicAdd(&scol[base + q * 512 + t], red[q * 512 + t]);
}

// ---------------- K2b (big): reduce partials -> 1/s ; pack V' ---------------
__global__ __launch_bounds__(256) void k2b_pack_p(
    const float* __restrict__ V,
    const float* __restrict__ partials,
    unsigned short* __restrict__ vf)
{
  __shared__ float sred[8 * 32];
  __shared__ float sinv[32];
  int t = threadIdx.x;
  int b = blockIdx.x >> 6;
  int kk = blockIdx.x & 63;

  {
    int tj = t & 31, tr = t >> 5;     // 8 rowblk-groups of 8
    float s = 0.f;
    #pragma unroll
    for (int q = 0; q < 8; ++q)
      s += partials[(size_t)(b * 64 + tr * 8 + q) * NN + kk * 32 + tj];
    sred[tr * 32 + tj] = s;
  }
  __syncthreads();
  if (t < 32) {
    float tot = 0.f;
    #pragma unroll
    for (int g = 0; g < 8; ++g) tot += sred[g * 32 + t];
    sinv[t] = (tot > 0.f) ? (1.0f / tot) : 0.0f;
  }
  __syncthreads();

  int ng = t >> 6;
  int l = t & 63;
  int jb0 = (l >> 4) * 8;             // 0,8,16,24 within the 32-col group
  int jb = kk * 32 + jb0;
  int o = ng * 16 + (l & 15);
  unsigned int pk[4];
  #pragma unroll
  for (int p = 0; p < 4; ++p) {
    int jr0 = jb + 2 * p, jr1 = jb + 2 * p + 1;
    float i0 = sinv[jb0 + 2 * p];
    float i1 = sinv[jb0 + 2 * p + 1];
    float v0 = V[(size_t)(b * NN + jr0) * FO + o] * i0;
    float v1 = V[(size_t)(b * NN + jr1) * FO + o] * i1;
    pk[p] = (unsigned int)f2bf(v0) | ((unsigned int)f2bf(v1) << 16);
  }
  *(uint4*)(vf + (size_t)(((b * 64 + kk) * 4 + ng) * 64 + l) * 8) =
      make_uint4(pk[0], pk[1], pk[2], pk[3]);
}

// ---------------- K2b (fallback): pack from scol (unchanged) ----------------
__global__ __launch_bounds__(256) void k2b_pack(
    const float* __restrict__ V,
    const float* __restrict__ scol,
    unsigned short* __restrict__ vf)
{
  int t = threadIdx.x;
  int b = blockIdx.x >> 6;
  int kk = blockIdx.x & 63;
  int ng = t >> 6;
  int l = t & 63;
  int jb = kk * 32 + ((l >> 4) * 8);
  int o = ng * 16 + (l & 15);
  unsigned int pk[4];
  #pragma unroll
  for (int p = 0; p < 4; ++p) {
    int jr0 = jb + 2 * p, jr1 = jb + 2 * p + 1;
    float s0 = scol[b * NN + jr0];
    float s1 = scol[b * NN + jr1];
    float i0 = (s0 > 0.f) ? (1.0f / s0) : 0.0f;
    float i1 = (s1 > 0.f) ? (1.0f / s1) : 0.0f;
    float v0 = V[(size_t)(b * NN + jr0) * FO + o] * i0;
    float v1 = V[(size_t)(b * NN + jr1) * FO + o] * i1;
    pk[p] = (unsigned int)f2bf(v0) | ((unsigned int)f2bf(v1) << 16);
  }
  *(uint4*)(vf + (size_t)(((b * 64 + kk) * 4 + ng) * 64 + l) * 8) =
      make_uint4(pk[0], pk[1], pk[2], pk[3]);
}

// ---------------- K3: out = relu(U @ V'), 32-row tiles ----------------------
__global__ __launch_bounds__(512, 4) void k3_agg_u3(
    const unsigned short* __restrict__ u_bf,
    const unsigned short* __restrict__ vf,
    float* __restrict__ outp)
{
  __shared__ float red[8 * 16 * 68];   // 34.8 KB
  int t = threadIdx.x;
  int b = blockIdx.x >> 6;
  int tt = blockIdx.x & 63;
  int i0 = tt * 32;
  int w = t >> 6, l = t & 63;
  int col = l & 15, quad = l >> 4;
  const unsigned short* urow0 = u_bf + (size_t)(b * NN + i0 + col) * NN + quad * 8;
  const unsigned short* urow1 = urow0 + (size_t)16 * NN;
  const unsigned short* vbase = vf + (size_t)(b * 64) * 2048 + l * 8;

  float4_t acc[2][4];
  #pragma unroll
  for (int sgi = 0; sgi < 2; ++sgi)
    #pragma unroll
    for (int g = 0; g < 4; ++g) acc[sgi][g] = (float4_t){0, 0, 0, 0};

  int kk0 = w * 8;
  short8_t A0 = *(const short8_t*)(urow0 + kk0 * 32);
  short8_t A1 = *(const short8_t*)(urow1 + kk0 * 32);
  const unsigned short* vb0 = vbase + (size_t)kk0 * 2048;
  short8_t c0 = *(const short8_t*)(vb0);
  short8_t c1 = *(const short8_t*)(vb0 + 512);
  short8_t c2 = *(const short8_t*)(vb0 + 1024);
  short8_t c3 = *(const short8_t*)(vb0 + 1536);

  #pragma unroll
  for (int s = 0; s < 8; ++s) {
    short8_t nA0, nA1, n0, n1, n2, n3;
    if (s < 7) {
      int kk = w * 8 + s + 1;
      nA0 = *(const short8_t*)(urow0 + kk * 32);
      nA1 = *(const short8_t*)(urow1 + kk * 32);
      const unsigned short* vn = vbase + (size_t)kk * 2048;
      n0 = *(const short8_t*)(vn);
      n1 = *(const short8_t*)(vn + 512);
      n2 = *(const short8_t*)(vn + 1024);
      n3 = *(const short8_t*)(vn + 1536);
    }
    acc[0][0] = __builtin_amdgcn_mfma_f32_16x16x32_bf16(A0, c0, acc[0][0], 0, 0, 0);
    acc[0][1] = __builtin_amdgcn_mfma_f32_16x16x32_bf16(A0, c1, acc[0][1], 0, 0, 0);
    acc[0][2] = __builtin_amdgcn_mfma_f32_16x16x32_bf16(A0, c2, acc[0][2], 0, 0, 0);
    acc[0][3] = __builtin_amdgcn_mfma_f32_16x16x32_bf16(A0, c3, acc[0][3], 0, 0, 0);
    acc[1][0] = __builtin_amdgcn_mfma_f32_16x16x32_bf16(A1, c0, acc[1][0], 0, 0, 0);
    acc[1][1] = __builtin_amdgcn_mfma_f32_16x16x32_bf16(A1, c1, acc[1][1], 0, 0, 0);
    acc[1][2] = __builtin_amdgcn_mfma_f32_16x16x32_bf16(A1, c2, acc[1][2], 0, 0, 0);
    acc[1][3] = __builtin_amdgcn_mfma_f32_16x16x32_bf16(A1, c3, acc[1][3], 0, 0, 0);
    if (s < 7) { A0 = nA0; A1 = nA1; c0 = n0; c1 = n1; c2 = n2; c3 = n3; }
  }

  #pragma unroll
  for (int sub = 0; sub < 2; ++sub) {
    __syncthreads();
    #pragma unroll
    for (int r = 0; r < 4; ++r) {
      int rowi = quad * 4 + r;
      float* rp = &red[w * 1088 + rowi * 68 + col];
      rp[0] = acc[sub][0][r];
      rp[16] = acc[sub][1][r];
      rp[32] = acc[sub][2][r];
      rp[48] = acc[sub][3][r];
    }
    __syncthreads();
    if (t < 256) {
      int row = t >> 4, o4 = (t & 15) * 4;
      const float* rp = &red[row * 68 + o4];
      float4 s0 = *(const float4*)(rp);
      float4 s1 = *(const float4*)(rp + 1088);
      float4 s2 = *(const float4*)(rp + 2176);
      float4 s3 = *(const float4*)(rp + 3264);
      float4 s4 = *(const float4*)(rp + 4352);
      float4 s5 = *(const float4*)(rp + 5440);
      float4 s6 = *(const float4*)(rp + 6528);
      float4 s7 = *(const float4*)(rp + 7616);
      float4 o;
      o.x = fmaxf(s0.x + s1.x + s2.x + s3.x + s4.x + s5.x + s6.x + s7.x, 0.0f);
      o.y = fmaxf(s0.y + s1.y + s2.y + s3.y + s4.y + s5.y + s6.y + s7.y, 0.0f);
      o.z = fmaxf(s0.z + s1.z + s2.z + s3.z + s4.z + s5.z + s6.z + s7.z, 0.0f);
      o.w = fmaxf(s0.w + s1.w + s2.w + s3.w + s4.w + s5.w + s6.w + s7.w, 0.0f);
      *(float4*)&outp[(size_t)(b * NN + i0 + sub * 16 + row) * FO + o4] = o;
    }
  }
}

// ---------------- K3b: fallback — recompute u from nt/f1/f2/bits -----------
__global__ __launch_bounds__(256) void k3_agg_b(
    const float* __restrict__ ntp,
    const unsigned char* __restrict__ bits,
    const float* __restrict__ f1,
    const float* __restrict__ f2,
    const unsigned short* __restrict__ vf,
    float* __restrict__ outp)
{
  __shared__ float red[4 * 16 * 68];
  int t = threadIdx.x;
  int b = blockIdx.x >> 7;
  int i0 = (blockIdx.x & 127) * 16;
  int w = t >> 6, l = t & 63;
  int col = l & 15, quad = l >> 4;
  int gi = b * NN + i0 + col;
  float f1v = f1[gi];
  const float* ntrow = ntp + (size_t)gi * NN;
  const unsigned char* brow = bits + (size_t)gi * (NN / 8);
  float4_t acc0 = {0, 0, 0, 0}, acc1 = {0, 0, 0, 0}, acc2 = {0, 0, 0, 0}, acc3 = {0, 0, 0, 0};

  for (int s = 0; s < 16; ++s) {
    int kk = w * 16 + s;
    int jq = kk * 32 + quad * 8;
    unsigned int m8 = brow[jq >> 3];
    float4 n0 = *(const float4*)(ntrow + jq);
    float4 n1 = *(const float4*)(ntrow + jq + 4);
    float4 g0 = *(const float4*)(f2 + b * NN + jq);
    float4 g1 = *(const float4*)(f2 + b * NN + jq + 4);
    float f2v[8] = {g0.x, g0.y, g0.z, g0.w, g1.x, g1.y, g1.z, g1.w};
    float ntf[8] = {n0.x, n0.y, n0.z, n0.w, n1.x, n1.y, n1.z, n1.w};
    union { unsigned int u[4]; short8_t v; } A;
    #pragma unroll
    for (int p = 0; p < 4; ++p) {
      int e0 = 2 * p, e1 = 2 * p + 1;
      float x0 = f1v + f2v[e0]; x0 = fmaxf(x0, 0.2f * x0);
      float u0 = ((m8 >> e0) & 1u) ? __expf(x0 * ntf[e0]) : 0.0f;
      float x1 = f1v + f2v[e1]; x1 = fmaxf(x1, 0.2f * x1);
      float u1 = ((m8 >> e1) & 1u) ? __expf(x1 * ntf[e1]) : 0.0f;
      A.u[p] = (unsigned int)f2bf(u0) | ((unsigned int)f2bf(u1) << 16);
    }
    const unsigned short* vb = vf + (size_t)(b * 64 + kk) * 2048 + l * 8;
    short8_t bf0 = *(const short8_t*)(vb);
    short8_t bf1 = *(const short8_t*)(vb + 512);
    short8_t bf2 = *(const short8_t*)(vb + 1024);
    short8_t bf3 = *(const short8_t*)(vb + 1536);
    acc0 = __builtin_amdgcn_mfma_f32_16x16x32_bf16(A.v, bf0, acc0, 0, 0, 0);
    acc1 = __builtin_amdgcn_mfma_f32_16x16x32_bf16(A.v, bf1, acc1, 0, 0, 0);
    acc2 = __builtin_amdgcn_mfma_f32_16x16x32_bf16(A.v, bf2, acc2, 0, 0, 0);
    acc3 = __builtin_amdgcn_mfma_f32_16x16x32_bf16(A.v, bf3, acc3, 0, 0, 0);
  }

  #pragma unroll
  for (int r = 0; r < 4; ++r) {
    int rowi = quad * 4 + r;
    red[w * 1088 + rowi * 68 + 0 + col] = acc0[r];
    red[w * 1088 + rowi * 68 + 16 + col] = acc1[r];
    red[w * 1088 + rowi * 68 + 32 + col] = acc2[r];
    red[w * 1088 + rowi * 68 + 48 + col] = acc3[r];
  }
  __syncthreads();

  int row = t >> 4, o4 = (t & 15) * 4;
  const float* rp = &red[row * 68 + o4];
  float4 s0 = *(const float4*)(rp);
  float4 s1 = *(const float4*)(rp + 1088);
  float4 s2 = *(const float4*)(rp + 2176);
  float4 s3 = *(const float4*)(rp + 3264);
  float4 o;
  o.x = fmaxf(s0.x + s1.x + s2.x + s3.x, 0.0f);
  o.y = fmaxf(s0.y + s1.y + s2.y + s3.y, 0.0f);
  o.z = fmaxf(s0.z + s1.z + s2.z + s3.z, 0.0f);
  o.w = fmaxf(s0.w + s1.w + s2.w + s3.w, 0.0f);
  *(float4*)&outp[(size_t)(b * NN + i0 + row) * FO + o4] = o;
}

extern "C" void kernel_launch(void* const* d_in, const int* in_sizes, int n_in,
                              void* d_out, int out_size, void* d_ws, size_t ws_size,
                              hipStream_t stream) {
  const float* h = (const float*)d_in[0];       // fp32 [B,N,FIN]
  const int* adj = (const int*)d_in[1];         // int32 [B,N,N]
  const float* level = (const float*)d_in[2];   // fp32 [B,N]
  const float* ntm = (const float*)d_in[3];     // fp32 [B,N,N]
  const float* W = (const float*)d_in[4];       // fp32 [FIN,FO]
  const float* a = (const float*)d_in[5];       // fp32 [2*FO,1]
  float* outp = (float*)d_out;

  float* V = (float*)d_ws;                              // 4 MB
  float* f1 = V + (size_t)BB * NN * FO;                 // 64 KB
  float* f2 = f1 + BB * NN;                             // 64 KB
  float* scol = f2 + BB * NN;                           // 64 KB (fallback)
  unsigned short* vf = (unsigned short*)(scol + BB * NN); // 2 MB
  float* partials = (float*)(vf + (size_t)BB * NN * FO);  // 4 MB
  unsigned int* abits = (unsigned int*)(partials + (size_t)BB * 64 * NN); // 4 MB
  char* tail = (char*)(abits + (size_t)BB * NN * (NN / 32));
  size_t fixed2 = (size_t)(tail - (char*)d_ws);
  size_t fixed1 = (size_t)((char*)abits - (char*)d_ws);
  size_t ubytes = (size_t)BB * NN * NN * 2;             // 67 MB
  bool big2 = (ws_size >= fixed2 + ubytes);
  bool big1 = (ws_size >= fixed1 + ubytes);

  if (big2) {
    unsigned short* u_bf = (unsigned short*)tail;
    k1_fused<<<5120, 256, 0, stream>>>(h, level, W, a, V, f1, f2, scol, adj, abits);
    k2a_stream<<<512, 512, 0, stream>>>(abits, ntm, f1, f2, u_bf, partials);
    k2b_pack_p<<<512, 256, 0, stream>>>(V, partials, vf);
    k3_agg_u3<<<512, 512, 0, stream>>>(u_bf, vf, outp);
  } else if (big1) {
    unsigned short* u_bf = (unsigned short*)abits;
    k1_fused<<<1024, 256, 0, stream>>>(h, level, W, a, V, f1, f2, scol, adj, abits);
    k2a_stream_adj<<<512, 512, 0, stream>>>(adj, ntm, f1, f2, u_bf, partials);
    k2b_pack_p<<<512, 256, 0, stream>>>(V, partials, vf);
    k3_agg_u3<<<512, 512, 0, stream>>>(u_bf, vf, outp);
  } else {
    unsigned char* bits = (unsigned char*)abits;        // 4 MB
    k1_fused<<<1024, 256, 0, stream>>>(h, level, W, a, V, f1, f2, scol, adj, abits);
    k2a_stats<0><<<512, 512, 0, stream>>>(adj, ntm, f1, f2, nullptr, bits, scol);
    k2b_pack<<<512, 256, 0, stream>>>(V, scol, vf);
    k3_agg_b<<<1024, 256, 0, stream>>>(ntm, bits, f1, f2, vf, outp);
  }
}